// Round 7
// baseline (87.833 us; speedup 1.0000x reference)
//
#include <hip/hip_runtime.h>
#include <math.h>

constexpr int B = 32, S = 4096, I = 512, H = 512;
constexpr int CH = 128;          // s-positions per workgroup in main pass
constexpr int NCH = S / CH;      // 32 chunks per batch row
constexpr float NEGV = -1e18f;

// workspace layout (float offsets)
constexpr size_t WS_WKD   = 0;       // [512]  Wk^T @ Wout
constexpr size_t WS_WQD   = 512;     // [512]  Wq^T @ Wout
constexpr size_t WS_CC    = 1024;    // [1]    (bq+bk)·Wout
constexpr size_t WS_PARTS = 2048;    // [B*NCH*514] m,l,ctx[512] main partials

// ---------------------------------------------------------------------------
// prep: 17 blocks. 0..7 -> wkd 64-col tiles (final), 8..15 -> wqd, 16 -> cc.
// Each tile block fully reduces its 64 columns over all 512 h -> no combine
// pass, no extra dispatch.
// ---------------------------------------------------------------------------
__global__ __launch_bounds__(256) void prep_kernel(
    const float* __restrict__ Wq, const float* __restrict__ bq,
    const float* __restrict__ Wk, const float* __restrict__ bk,
    const float* __restrict__ Wout, float* __restrict__ ws) {
  __shared__ float sh[256];
  int blk = blockIdx.x;
  int t = threadIdx.x, wv = t >> 6, ln = t & 63;

  if (blk < 16) {
    bool isQ = blk >= 8;
    const float* W = isQ ? Wq : Wk;
    float* out = ws + (isQ ? WS_WQD : WS_WKD);
    int j = (blk & 7) * 64;
    float p = 0.f;
    int h0 = wv * 128;
    #pragma unroll 4
    for (int h = h0; h < h0 + 128; ++h)
      p = fmaf(W[(size_t)h * I + j + ln], Wout[h], p);
    sh[wv * 64 + ln] = p;
    __syncthreads();
    if (t < 64) out[j + t] = sh[t] + sh[64 + t] + sh[128 + t] + sh[192 + t];
  } else {
    float p = 0.f;
    for (int h = t; h < H; h += 256) p = fmaf(bq[h] + bk[h], Wout[h], p);
    sh[t] = p;
    __syncthreads();
    for (int o = 128; o; o >>= 1) {
      if (t < o) sh[t] += sh[t + o];
      __syncthreads();
    }
    if (t == 0) ws[WS_CC] = sh[0];
  }
}

// ---------------------------------------------------------------------------
// main: one pass over key. 4 waves/block, 2 rows/wave/iter, 16 iters.
// Depth-2 register pipeline (8 dwordx4 = 8 KB in flight per wave).
// __launch_bounds__(256,4): 128-VGPR cap. (256,8) squeezed to 32 VGPR and
// spilled everything -> 473 MB scratch traffic, 2.1 TB/s. Do not raise.
// ---------------------------------------------------------------------------
__global__ __launch_bounds__(256, 4) void main_kernel(
    const float* __restrict__ query,
    const float* __restrict__ key, const int* __restrict__ mask,
    float* __restrict__ ws, float* __restrict__ attn_w) {
  const float* wkd = ws + WS_WKD;
  const float* wqd = ws + WS_WQD;
  float* parts = ws + WS_PARTS;

  int b = blockIdx.x, cidx = blockIdx.y;
  int t = threadIdx.x, wv = t >> 6, ln = t & 63;

  // per-wave redundant off[b] = query[b,:]·wqd + cc   (L2-hot)
  float offb;
  {
    const float* qb = query + (size_t)b * I;
    float p = qb[ln] * wqd[ln];
    #pragma unroll
    for (int k = 1; k < 8; ++k)
      p = fmaf(qb[ln + 64 * k], wqd[ln + 64 * k], p);
    #pragma unroll
    for (int o = 32; o; o >>= 1) p += __shfl_xor(p, o, 64);
    offb = p + ws[WS_CC];
  }

  const float* kb = key + ((size_t)b * S + (size_t)cidx * CH) * I;
  const int* mrow = mask + (size_t)b * S + cidx * CH;
  float* awrow = attn_w + (size_t)b * S + cidx * CH;

  float4 wA = *(const float4*)(wkd + ln * 4);
  float4 wB = *(const float4*)(wkd + 256 + ln * 4);

  float m = -INFINITY, l = 0.f;
  float4 cA = {0.f, 0.f, 0.f, 0.f}, cB = {0.f, 0.f, 0.f, 0.f};

  constexpr int NIT = CH / 8;        // 16 iterations
  const float* lanep = kb + (size_t)(wv * 2) * I + ln * 4;
  constexpr int ROWSTEP = 8 * I;     // floats per iteration step

  // prologue: iters 0 (u) and 1 (v)
  float4 uA0 = *(const float4*)(lanep);
  float4 uB0 = *(const float4*)(lanep + 256);
  float4 uA1 = *(const float4*)(lanep + 512);
  float4 uB1 = *(const float4*)(lanep + 768);
  float4 vA0 = *(const float4*)(lanep + ROWSTEP);
  float4 vB0 = *(const float4*)(lanep + ROWSTEP + 256);
  float4 vA1 = *(const float4*)(lanep + ROWSTEP + 512);
  float4 vB1 = *(const float4*)(lanep + ROWSTEP + 768);

  #pragma unroll 2
  for (int it = 0; it < NIT; ++it) {
    int s = wv * 2 + it * 8;
    int itn = (it + 2 < NIT) ? it + 2 : it;   // clamped tail prefetch (L2-hot)
    const float* kn = lanep + (size_t)itn * ROWSTEP;
    float4 nA0 = *(const float4*)(kn);
    float4 nB0 = *(const float4*)(kn + 256);
    float4 nA1 = *(const float4*)(kn + 512);
    float4 nB1 = *(const float4*)(kn + 768);

    float d0 = uA0.x * wA.x, d1 = uA1.x * wA.x;
    d0 = fmaf(uA0.y, wA.y, d0); d1 = fmaf(uA1.y, wA.y, d1);
    d0 = fmaf(uA0.z, wA.z, d0); d1 = fmaf(uA1.z, wA.z, d1);
    d0 = fmaf(uA0.w, wA.w, d0); d1 = fmaf(uA1.w, wA.w, d1);
    d0 = fmaf(uB0.x, wB.x, d0); d1 = fmaf(uB1.x, wB.x, d1);
    d0 = fmaf(uB0.y, wB.y, d0); d1 = fmaf(uB1.y, wB.y, d1);
    d0 = fmaf(uB0.z, wB.z, d0); d1 = fmaf(uB1.z, wB.z, d1);
    d0 = fmaf(uB0.w, wB.w, d0); d1 = fmaf(uB1.w, wB.w, d1);
    #pragma unroll
    for (int o = 32; o; o >>= 1) {
      d0 += __shfl_xor(d0, o, 64);
      d1 += __shfl_xor(d1, o, 64);
    }

    int2 mm = *(const int2*)(mrow + s);
    float s0 = mm.x ? NEGV : (offb + d0);
    float s1 = mm.y ? NEGV : (offb + d1);
    if (ln == 0) *(float2*)(awrow + s) = float2{s0, s1};

    float mx = fmaxf(s0, s1);
    if (mx > m) {                               // wave-uniform, rare
      float sc = __expf(m - mx);                // exp(-inf)=0 handles init
      l *= sc;
      cA.x *= sc; cA.y *= sc; cA.z *= sc; cA.w *= sc;
      cB.x *= sc; cB.y *= sc; cB.z *= sc; cB.w *= sc;
      m = mx;
    }
    float e0 = __expf(s0 - m);
    float e1 = __expf(s1 - m);
    l += e0 + e1;
    cA.x = fmaf(e0, uA0.x, fmaf(e1, uA1.x, cA.x));
    cA.y = fmaf(e0, uA0.y, fmaf(e1, uA1.y, cA.y));
    cA.z = fmaf(e0, uA0.z, fmaf(e1, uA1.z, cA.z));
    cA.w = fmaf(e0, uA0.w, fmaf(e1, uA1.w, cA.w));
    cB.x = fmaf(e0, uB0.x, fmaf(e1, uB1.x, cB.x));
    cB.y = fmaf(e0, uB0.y, fmaf(e1, uB1.y, cB.y));
    cB.z = fmaf(e0, uB0.z, fmaf(e1, uB1.z, cB.z));
    cB.w = fmaf(e0, uB0.w, fmaf(e1, uB1.w, cB.w));

    // rotate pipeline registers (renamed away by the unroll)
    uA0 = vA0; uB0 = vB0; uA1 = vA1; uB1 = vB1;
    vA0 = nA0; vB0 = nB0; vA1 = nA1; vB1 = nB1;
  }

  // combine the 4 waves' online states into one block partial
  __shared__ float shm[4], shl[4];
  __shared__ float shc[4][512];
  if (ln == 0) { shm[wv] = m; shl[wv] = l; }
  *(float4*)&shc[wv][ln * 4] = cA;
  *(float4*)&shc[wv][256 + ln * 4] = cB;
  __syncthreads();

  float mb = fmaxf(fmaxf(shm[0], shm[1]), fmaxf(shm[2], shm[3]));
  float ew0 = __expf(shm[0] - mb), ew1 = __expf(shm[1] - mb);
  float ew2 = __expf(shm[2] - mb), ew3 = __expf(shm[3] - mb);
  float* slot = parts + ((size_t)b * NCH + cidx) * 514;
  if (t == 0) {
    slot[0] = mb;
    slot[1] = shl[0] * ew0 + shl[1] * ew1 + shl[2] * ew2 + shl[3] * ew3;
  }
  for (int i = t; i < I; i += 256) {
    float acc = shc[0][i] * ew0;
    acc = fmaf(shc[1][i], ew1, acc);
    acc = fmaf(shc[2][i], ew2, acc);
    acc = fmaf(shc[3][i], ew3, acc);
    slot[2 + i] = acc;
  }
}

// ---------------------------------------------------------------------------
// finish: grid (B, 2), 256 threads. Phase 1: combine NCH chunk-partials
// -> normalized ctx[512] in LDS (2x redundant across the two h-half blocks).
// Phase 2: attn[b,h] = ctx·Wk[h,:] + bk[h], one thread per h, Wk ROW reads
// (contiguous per thread, L1-amortized; no transpose needed anywhere).
// ---------------------------------------------------------------------------
__global__ __launch_bounds__(256) void finish_kernel(
    const float* __restrict__ Wk, const float* __restrict__ bk,
    float* __restrict__ ws, float* __restrict__ attn) {
  const float* parts = ws + WS_PARTS;
  int b = blockIdx.x, hq = blockIdx.y, t = threadIdx.x;

  __shared__ float eld[NCH], ctx[I];
  const float* pb = parts + (size_t)b * NCH * 514;

  // every thread computes m, l (broadcast loads)
  float m = -INFINITY;
  #pragma unroll 8
  for (int p = 0; p < NCH; ++p) m = fmaxf(m, pb[p * 514]);
  float l = 0.f;
  #pragma unroll 8
  for (int p = 0; p < NCH; ++p) l = fmaf(pb[p * 514 + 1], __expf(pb[p * 514] - m), l);
  float invl = 1.f / l;
  if (t < NCH) eld[t] = __expf(pb[t * 514] - m) * invl;   // invl folded in
  __syncthreads();

  // ctx: thread owns i = t and i = t+256; NCH independent loads each
  {
    float a0 = 0.f, a1 = 0.f;
    #pragma unroll 8
    for (int p = 0; p < NCH; ++p) {
      float e = eld[p];
      a0 = fmaf(pb[p * 514 + 2 + t], e, a0);
      a1 = fmaf(pb[p * 514 + 258 + t], e, a1);
    }
    ctx[t] = a0;
    ctx[t + 256] = a1;
  }
  __syncthreads();

  // GEMV: thread t -> h = hq*256 + t; row-contiguous Wk reads,
  // 4 split accumulators to break the fma chain.
  int h = hq * 256 + t;
  const float4* wrow = (const float4*)(Wk + (size_t)h * I);
  float a0 = 0.f, a1 = 0.f, a2 = 0.f, a3 = 0.f;
  #pragma unroll 8
  for (int c = 0; c < 128; c += 4) {
    float4 w0 = wrow[c],     x0 = *(const float4*)(ctx + c * 4);
    float4 w1 = wrow[c + 1], x1 = *(const float4*)(ctx + c * 4 + 4);
    float4 w2 = wrow[c + 2], x2 = *(const float4*)(ctx + c * 4 + 8);
    float4 w3 = wrow[c + 3], x3 = *(const float4*)(ctx + c * 4 + 12);
    a0 = fmaf(w0.x, x0.x, fmaf(w0.y, x0.y, fmaf(w0.z, x0.z, fmaf(w0.w, x0.w, a0))));
    a1 = fmaf(w1.x, x1.x, fmaf(w1.y, x1.y, fmaf(w1.z, x1.z, fmaf(w1.w, x1.w, a1))));
    a2 = fmaf(w2.x, x2.x, fmaf(w2.y, x2.y, fmaf(w2.z, x2.z, fmaf(w2.w, x2.w, a2))));
    a3 = fmaf(w3.x, x3.x, fmaf(w3.y, x3.y, fmaf(w3.z, x3.z, fmaf(w3.w, x3.w, a3))));
  }
  attn[(size_t)b * H + h] = (a0 + a1) + (a2 + a3) + bk[h];
}

// ---------------------------------------------------------------------------
extern "C" void kernel_launch(void* const* d_in, const int* in_sizes, int n_in,
                              void* d_out, int out_size, void* d_ws, size_t ws_size,
                              hipStream_t stream) {
  const float* query = (const float*)d_in[0];   // [B, I]
  const float* key   = (const float*)d_in[1];   // [B, S, I]
  const int*   mask  = (const int*)d_in[2];     // [B, S]
  const float* Wq    = (const float*)d_in[3];   // [H, I]
  const float* bq    = (const float*)d_in[4];   // [H]
  const float* Wk    = (const float*)d_in[5];   // [H, I]
  const float* bk    = (const float*)d_in[6];   // [H]
  const float* Wout  = (const float*)d_in[7];   // [H]

  float* attn   = (float*)d_out;                // [B, H]
  float* attn_w = (float*)d_out + (size_t)B * H;// [B, S]
  float* ws     = (float*)d_ws;

  prep_kernel<<<17, 256, 0, stream>>>(Wq, bq, Wk, bk, Wout, ws);
  main_kernel<<<dim3(B, NCH), 256, 0, stream>>>(query, key, mask, ws, attn_w);
  finish_kernel<<<dim3(B, 2), 256, 0, stream>>>(Wk, bk, ws, attn);
}

// Round 8
// 70.216 us; speedup vs baseline: 1.2509x; 1.2509x over previous
//
#include <hip/hip_runtime.h>
#include <math.h>

constexpr int B = 32, S = 4096, I = 512, H = 512;
constexpr int CH = 128;          // s-positions per workgroup in main pass
constexpr int NCH = S / CH;      // 32 chunks per batch row
constexpr float NEGV = -1e18f;

// workspace layout (float offsets)
constexpr size_t WS_WKD   = 0;       // [512]  Wk^T @ Wout
constexpr size_t WS_WQD   = 512;     // [512]  Wq^T @ Wout
constexpr size_t WS_CC    = 1024;    // [1]    (bq+bk)·Wout
constexpr size_t WS_PARTS = 2048;    // [B*NCH*514] m,l,ctx[512] main partials

// ---------------------------------------------------------------------------
// prep: 17 blocks. 0..7 -> wkd 64-col tiles, 8..15 -> wqd, 16 -> cc.
// Column-dot over h: 16 loads batched into registers per round so 16 are
// outstanding (was 4 -> 32 latency-serialized rounds = ~12us; now ~8 rounds).
// ---------------------------------------------------------------------------
__global__ __launch_bounds__(256) void prep_kernel(
    const float* __restrict__ Wq, const float* __restrict__ bq,
    const float* __restrict__ Wk, const float* __restrict__ bk,
    const float* __restrict__ Wout, float* __restrict__ ws) {
  __shared__ float sh[256];
  int blk = blockIdx.x;
  int t = threadIdx.x, wv = t >> 6, ln = t & 63;

  if (blk < 16) {
    bool isQ = blk >= 8;
    const float* W = isQ ? Wq : Wk;
    float* out = ws + (isQ ? WS_WQD : WS_WKD);
    int j = (blk & 7) * 64 + ln;
    int h0 = wv * 128;
    float p = 0.f;
    for (int hb = 0; hb < 128; hb += 16) {
      float v[16];
      #pragma unroll
      for (int r = 0; r < 16; ++r)
        v[r] = W[(size_t)(h0 + hb + r) * I + j];
      #pragma unroll
      for (int r = 0; r < 16; ++r)
        p = fmaf(v[r], Wout[h0 + hb + r], p);
    }
    sh[wv * 64 + ln] = p;
    __syncthreads();
    if (t < 64) out[(blk & 7) * 64 + t] = sh[t] + sh[64 + t] + sh[128 + t] + sh[192 + t];
  } else {
    float p = 0.f;
    for (int h = t; h < H; h += 256) p = fmaf(bq[h] + bk[h], Wout[h], p);
    sh[t] = p;
    __syncthreads();
    for (int o = 128; o; o >>= 1) {
      if (t < o) sh[t] += sh[t + o];
      __syncthreads();
    }
    if (t == 0) ws[WS_CC] = sh[0];
  }
}

// ---------------------------------------------------------------------------
// main: one pass over key. 4 waves/block, 2 rows/wave/iter, 16 iters.
// Depth-2 register pipeline (8 dwordx4 = 8 KB in flight per wave).
// __launch_bounds__(256,4): 128-VGPR cap. (256,8) squeezed to 32 VGPR and
// spilled everything -> 473 MB scratch traffic, 2.1 TB/s. Do not raise.
// ---------------------------------------------------------------------------
__global__ __launch_bounds__(256, 4) void main_kernel(
    const float* __restrict__ query,
    const float* __restrict__ key, const int* __restrict__ mask,
    float* __restrict__ ws, float* __restrict__ attn_w) {
  const float* wkd = ws + WS_WKD;
  const float* wqd = ws + WS_WQD;
  float* parts = ws + WS_PARTS;

  int b = blockIdx.x, cidx = blockIdx.y;
  int t = threadIdx.x, wv = t >> 6, ln = t & 63;

  // per-wave redundant off[b] = query[b,:]·wqd + cc   (L2-hot)
  float offb;
  {
    const float* qb = query + (size_t)b * I;
    float p = qb[ln] * wqd[ln];
    #pragma unroll
    for (int k = 1; k < 8; ++k)
      p = fmaf(qb[ln + 64 * k], wqd[ln + 64 * k], p);
    #pragma unroll
    for (int o = 32; o; o >>= 1) p += __shfl_xor(p, o, 64);
    offb = p + ws[WS_CC];
  }

  const float* kb = key + ((size_t)b * S + (size_t)cidx * CH) * I;
  const int* mrow = mask + (size_t)b * S + cidx * CH;
  float* awrow = attn_w + (size_t)b * S + cidx * CH;

  float4 wA = *(const float4*)(wkd + ln * 4);
  float4 wB = *(const float4*)(wkd + 256 + ln * 4);

  float m = -INFINITY, l = 0.f;
  float4 cA = {0.f, 0.f, 0.f, 0.f}, cB = {0.f, 0.f, 0.f, 0.f};

  constexpr int NIT = CH / 8;        // 16 iterations
  const float* lanep = kb + (size_t)(wv * 2) * I + ln * 4;
  constexpr int ROWSTEP = 8 * I;     // floats per iteration step

  // prologue: iters 0 (u) and 1 (v)
  float4 uA0 = *(const float4*)(lanep);
  float4 uB0 = *(const float4*)(lanep + 256);
  float4 uA1 = *(const float4*)(lanep + 512);
  float4 uB1 = *(const float4*)(lanep + 768);
  float4 vA0 = *(const float4*)(lanep + ROWSTEP);
  float4 vB0 = *(const float4*)(lanep + ROWSTEP + 256);
  float4 vA1 = *(const float4*)(lanep + ROWSTEP + 512);
  float4 vB1 = *(const float4*)(lanep + ROWSTEP + 768);

  #pragma unroll 2
  for (int it = 0; it < NIT; ++it) {
    int s = wv * 2 + it * 8;
    int itn = (it + 2 < NIT) ? it + 2 : it;   // clamped tail prefetch (L2-hot)
    const float* kn = lanep + (size_t)itn * ROWSTEP;
    float4 nA0 = *(const float4*)(kn);
    float4 nB0 = *(const float4*)(kn + 256);
    float4 nA1 = *(const float4*)(kn + 512);
    float4 nB1 = *(const float4*)(kn + 768);

    float d0 = uA0.x * wA.x, d1 = uA1.x * wA.x;
    d0 = fmaf(uA0.y, wA.y, d0); d1 = fmaf(uA1.y, wA.y, d1);
    d0 = fmaf(uA0.z, wA.z, d0); d1 = fmaf(uA1.z, wA.z, d1);
    d0 = fmaf(uA0.w, wA.w, d0); d1 = fmaf(uA1.w, wA.w, d1);
    d0 = fmaf(uB0.x, wB.x, d0); d1 = fmaf(uB1.x, wB.x, d1);
    d0 = fmaf(uB0.y, wB.y, d0); d1 = fmaf(uB1.y, wB.y, d1);
    d0 = fmaf(uB0.z, wB.z, d0); d1 = fmaf(uB1.z, wB.z, d1);
    d0 = fmaf(uB0.w, wB.w, d0); d1 = fmaf(uB1.w, wB.w, d1);
    #pragma unroll
    for (int o = 32; o; o >>= 1) {
      d0 += __shfl_xor(d0, o, 64);
      d1 += __shfl_xor(d1, o, 64);
    }

    int2 mm = *(const int2*)(mrow + s);
    float s0 = mm.x ? NEGV : (offb + d0);
    float s1 = mm.y ? NEGV : (offb + d1);
    if (ln == 0) *(float2*)(awrow + s) = float2{s0, s1};

    float mx = fmaxf(s0, s1);
    if (mx > m) {                               // wave-uniform, rare
      float sc = __expf(m - mx);                // exp(-inf)=0 handles init
      l *= sc;
      cA.x *= sc; cA.y *= sc; cA.z *= sc; cA.w *= sc;
      cB.x *= sc; cB.y *= sc; cB.z *= sc; cB.w *= sc;
      m = mx;
    }
    float e0 = __expf(s0 - m);
    float e1 = __expf(s1 - m);
    l += e0 + e1;
    cA.x = fmaf(e0, uA0.x, fmaf(e1, uA1.x, cA.x));
    cA.y = fmaf(e0, uA0.y, fmaf(e1, uA1.y, cA.y));
    cA.z = fmaf(e0, uA0.z, fmaf(e1, uA1.z, cA.z));
    cA.w = fmaf(e0, uA0.w, fmaf(e1, uA1.w, cA.w));
    cB.x = fmaf(e0, uB0.x, fmaf(e1, uB1.x, cB.x));
    cB.y = fmaf(e0, uB0.y, fmaf(e1, uB1.y, cB.y));
    cB.z = fmaf(e0, uB0.z, fmaf(e1, uB1.z, cB.z));
    cB.w = fmaf(e0, uB0.w, fmaf(e1, uB1.w, cB.w));

    // rotate pipeline registers (renamed away by the unroll)
    uA0 = vA0; uB0 = vB0; uA1 = vA1; uB1 = vB1;
    vA0 = nA0; vB0 = nB0; vA1 = nA1; vB1 = nB1;
  }

  // combine the 4 waves' online states into one block partial
  __shared__ float shm[4], shl[4];
  __shared__ float shc[4][512];
  if (ln == 0) { shm[wv] = m; shl[wv] = l; }
  *(float4*)&shc[wv][ln * 4] = cA;
  *(float4*)&shc[wv][256 + ln * 4] = cB;
  __syncthreads();

  float mb = fmaxf(fmaxf(shm[0], shm[1]), fmaxf(shm[2], shm[3]));
  float ew0 = __expf(shm[0] - mb), ew1 = __expf(shm[1] - mb);
  float ew2 = __expf(shm[2] - mb), ew3 = __expf(shm[3] - mb);
  float* slot = parts + ((size_t)b * NCH + cidx) * 514;
  if (t == 0) {
    slot[0] = mb;
    slot[1] = shl[0] * ew0 + shl[1] * ew1 + shl[2] * ew2 + shl[3] * ew3;
  }
  for (int i = t; i < I; i += 256) {
    float acc = shc[0][i] * ew0;
    acc = fmaf(shc[1][i], ew1, acc);
    acc = fmaf(shc[2][i], ew2, acc);
    acc = fmaf(shc[3][i], ew3, acc);
    slot[2 + i] = acc;
  }
}

// ---------------------------------------------------------------------------
// finish: grid (B, 8), 256 threads. Phase 1: combine NCH chunk-partials
// -> normalized ctx[512] in LDS (8x redundant, cheap: 66 KB L2 per block).
// Phase 2: attn[b,h] = ctx·Wk[h,:] + bk[h]. 4 threads per Wk row with
// INTERLEAVED 16B chunks (adjacent lanes -> adjacent 16B -> full 64B lines),
// quarter-sums combined via shfl_xor. Per block only 64 rows = 128 KB.
// ---------------------------------------------------------------------------
__global__ __launch_bounds__(256) void finish_kernel(
    const float* __restrict__ Wk, const float* __restrict__ bk,
    float* __restrict__ ws, float* __restrict__ attn) {
  const float* parts = ws + WS_PARTS;
  int b = blockIdx.x, hq = blockIdx.y, t = threadIdx.x;

  __shared__ float eld[NCH];
  __shared__ __align__(16) float ctx[I];
  const float* pb = parts + (size_t)b * NCH * 514;

  // every thread computes m, l (broadcast loads)
  float m = -INFINITY;
  #pragma unroll 8
  for (int p = 0; p < NCH; ++p) m = fmaxf(m, pb[p * 514]);
  float l = 0.f;
  #pragma unroll 8
  for (int p = 0; p < NCH; ++p) l = fmaf(pb[p * 514 + 1], __expf(pb[p * 514] - m), l);
  float invl = 1.f / l;
  if (t < NCH) eld[t] = __expf(pb[t * 514] - m) * invl;   // invl folded in
  __syncthreads();

  // ctx: thread owns i = t and i = t+256; NCH independent loads each
  {
    float a0 = 0.f, a1 = 0.f;
    #pragma unroll 8
    for (int p = 0; p < NCH; ++p) {
      float e = eld[p];
      a0 = fmaf(pb[p * 514 + 2 + t], e, a0);
      a1 = fmaf(pb[p * 514 + 258 + t], e, a1);
    }
    ctx[t] = a0;
    ctx[t + 256] = a1;
  }
  __syncthreads();

  // GEMV: h = hq*64 + t/4; quarter q = t&3 reads chunks q, q+4, q+8, ...
  int h = hq * 64 + (t >> 2), q = t & 3;
  const float4* wrow = (const float4*)(Wk + (size_t)h * I);
  const float4* cvec = (const float4*)ctx;
  float a0 = 0.f, a1 = 0.f;
  #pragma unroll 8
  for (int c = 0; c < 32; c += 2) {
    float4 w0 = wrow[q + 4 * c];
    float4 w1 = wrow[q + 4 * (c + 1)];
    float4 x0 = cvec[q + 4 * c];
    float4 x1 = cvec[q + 4 * (c + 1)];
    a0 = fmaf(w0.x, x0.x, fmaf(w0.y, x0.y, fmaf(w0.z, x0.z, fmaf(w0.w, x0.w, a0))));
    a1 = fmaf(w1.x, x1.x, fmaf(w1.y, x1.y, fmaf(w1.z, x1.z, fmaf(w1.w, x1.w, a1))));
  }
  float a = a0 + a1;
  a += __shfl_xor(a, 1, 64);
  a += __shfl_xor(a, 2, 64);
  if (q == 0) attn[(size_t)b * H + h] = a + bk[h];
}

// ---------------------------------------------------------------------------
extern "C" void kernel_launch(void* const* d_in, const int* in_sizes, int n_in,
                              void* d_out, int out_size, void* d_ws, size_t ws_size,
                              hipStream_t stream) {
  const float* query = (const float*)d_in[0];   // [B, I]
  const float* key   = (const float*)d_in[1];   // [B, S, I]
  const int*   mask  = (const int*)d_in[2];     // [B, S]
  const float* Wq    = (const float*)d_in[3];   // [H, I]
  const float* bq    = (const float*)d_in[4];   // [H]
  const float* Wk    = (const float*)d_in[5];   // [H, I]
  const float* bk    = (const float*)d_in[6];   // [H]
  const float* Wout  = (const float*)d_in[7];   // [H]

  float* attn   = (float*)d_out;                // [B, H]
  float* attn_w = (float*)d_out + (size_t)B * H;// [B, S]
  float* ws     = (float*)d_ws;

  prep_kernel<<<17, 256, 0, stream>>>(Wq, bq, Wk, bk, Wout, ws);
  main_kernel<<<dim3(B, NCH), 256, 0, stream>>>(query, key, mask, ws, attn_w);
  finish_kernel<<<dim3(B, 8), 256, 0, stream>>>(Wk, bk, ws, attn);
}